// Round 4
// baseline (2359.219 us; speedup 1.0000x reference)
//
#include <hip/hip_runtime.h>
#include <hip/hip_bf16.h>

#define NN 131072   // total nodes (1024 graphs x 128)
#define NG 1024     // graphs
#define NE 1048576  // edges per edge set

typedef __hip_bfloat16 bf16;

__device__ __forceinline__ float b2f(bf16 v){ return __bfloat162float(v); }
__device__ __forceinline__ bf16 f2b(float v){ return __float2bfloat16(v); }
__device__ __forceinline__ float eluf(float x){ return x > 0.f ? x : expm1f(x); }
__device__ __forceinline__ float lrelu(float x){ return x >= 0.f ? x : 0.2f*x; }

// flag-dispatched load: f=1 -> buffer is float32, f=0 -> bf16
__device__ __forceinline__ float ldx(const void* p, size_t i, int f){
  return f ? ((const float*)p)[i] : b2f(((const bf16*)p)[i]);
}

// ---------------- input dtype probe ----------------
// bf16 N(0,1) data: exponents cluster near 0x7F; f32 data viewed as bf16 has
// pseudo-random exponent bits in every even element. Count implausible exponents.
__global__ void detect_dtype(const unsigned short* __restrict__ x, int* __restrict__ flag){
  if (blockIdx.x==0 && threadIdx.x==0){
    int bad = 0;
    for (int i=0;i<2048;i++){
      unsigned short e = (x[i] >> 7) & 0xFF;
      if (e == 0xFF) bad++;                   // inf/nan
      else if (e >= 0x90) bad++;              // |v| >= 2^17
      else if (e != 0 && e < 0x60) bad++;     // 0 < |v| < 2^-31
    }
    *flag = (bad > 64) ? 1 : 0;
  }
}

__global__ __launch_bounds__(256) void zero_ints(int* __restrict__ p, int n){
  int i = blockIdx.x*256 + threadIdx.x;
  if (i < n) p[i] = 0;
}

// ---------------- CSR build (counting sort by dst), single edge set ----------------
__global__ __launch_bounds__(256) void hist1(const int* __restrict__ dp, int* __restrict__ counts){
  int e = blockIdx.x*256 + threadIdx.x;
  atomicAdd(&counts[dp[e]], 1);
}

__global__ __launch_bounds__(256) void scan_a(const int* __restrict__ counts, int* __restrict__ offs, int* __restrict__ bsums){
  __shared__ int sh[256];
  int b = blockIdx.x, t = threadIdx.x;
  int i = b*256 + t;
  int v = counts[i];
  int val = v; sh[t] = v; __syncthreads();
  for (int d=1; d<256; d<<=1){
    int add = (t >= d) ? sh[t-d] : 0;
    __syncthreads();
    val += add; sh[t] = val;
    __syncthreads();
  }
  offs[i] = val - v;
  if (t == 255) bsums[b] = val;
}

__global__ __launch_bounds__(512) void scan_b(int* __restrict__ bsums){
  __shared__ int sh[512];
  int t = threadIdx.x;
  int v = bsums[t];
  int val = v; sh[t] = v; __syncthreads();
  for (int d=1; d<512; d<<=1){
    int add = (t >= d) ? sh[t-d] : 0;
    __syncthreads();
    val += add; sh[t] = val;
    __syncthreads();
  }
  bsums[t] = val - v;
}

__global__ __launch_bounds__(256) void scan_c(int* __restrict__ offs, const int* __restrict__ bsums, int* __restrict__ cursor){
  int i = blockIdx.x*256 + threadIdx.x;
  int v = offs[i] + bsums[blockIdx.x];
  offs[i] = v;
  cursor[i] = v;
  if (i == 0) offs[NN] = NE;
}

__global__ __launch_bounds__(256) void scatter1(const int* __restrict__ sp, const int* __restrict__ dp,
                                                int* __restrict__ cursor, int* __restrict__ srcs){
  int e = blockIdx.x*256 + threadIdx.x;
  int p = atomicAdd(&cursor[dp[e]], 1);
  srcs[p] = sp[e];
}

// ---------------- weight prep (flag-dispatched reads) ----------------
// sm layout (floats): 0 att_is[64] | 64 att_id[64] | 128 att_xs[64] | 192 att_ps[128] |
//                     320 att_pd[128] | 448 b_intra[64] | 512 b_inter[64] | 576 b_pool[128] |
//                     704 ln_w[128] | 832 ln_b[128]
__global__ __launch_bounds__(256) void prep_kernel(
    const void* w_intra, const void* w_isrc, const void* w_idst, const void* att_xd, const void* w_pool,
    const void* att_is, const void* att_id, const void* att_xs,
    const void* att_ps, const void* att_pd,
    const void* b_intra, const void* b_inter, const void* b_pool,
    const void* ln_w, const void* ln_b,
    float* __restrict__ Wc1, float* __restrict__ Wp, float* __restrict__ vdst, float* __restrict__ sm,
    const int* __restrict__ fp){
  int f = *fp;
  int t = threadIdx.x;
  for (int i=t; i<16384; i+=256){
    int k = i>>7, j = i&127;
    Wc1[i] = (j < 64) ? ldx(w_intra, k*64 + j, f) : ldx(w_isrc, k*64 + (j-64), f);
    Wp[i]  = ldx(w_pool, i, f);
  }
  {
    int k = t>>1, h = t&1; float a = 0.f;
    for (int c=0;c<32;c++) a += ldx(w_idst, k*64 + h*32 + c, f) * ldx(att_xd, h*32 + c, f);
    vdst[t] = a;
  }
  if (t < 64){
    sm[t]     = ldx(att_is, t, f);
    sm[64+t]  = ldx(att_id, t, f);
    sm[128+t] = ldx(att_xs, t, f);
    sm[448+t] = ldx(b_intra, t, f);
    sm[512+t] = ldx(b_inter, t, f);
  }
  if (t < 128){
    sm[192+t] = ldx(att_ps, t, f);
    sm[320+t] = ldx(att_pd, t, f);
    sm[576+t] = ldx(b_pool, t, f);
    sm[704+t] = ldx(ln_w, t, f);
    sm[832+t] = ldx(ln_b, t, f);
  }
}

// ---------------- GEMM: C[N,128] = act(A[N,128]) @ W[128,128] ----------------
// A read is flag-dispatched when fp!=null (raw inputs); fp==null -> bf16 internal.
template<bool ELU>
__global__ __launch_bounds__(256) void gemm128(const void* A, const float* __restrict__ W, bf16* __restrict__ C,
                                               const int* __restrict__ fp){
  int f = fp ? *fp : 0;
  __shared__ float sA[64][33];
  __shared__ float sW[32][128];
  int tid = threadIdx.x;
  int tx = tid & 31, ty = tid >> 5;
  size_t row0 = (size_t)blockIdx.x * 64;
  float acc[8][4] = {};
  for (int k0 = 0; k0 < 128; k0 += 32){
    #pragma unroll
    for (int i=0;i<8;i++){
      int idx = tid + i*256;
      int r = idx >> 5, kk = idx & 31;
      float v = ldx(A, (row0 + r)*128 + k0 + kk, f);
      if (ELU) v = eluf(v);
      sA[r][kk] = v;
    }
    #pragma unroll
    for (int i=0;i<16;i++){
      int idx = tid + i*256;
      int kr = idx >> 7, c = idx & 127;
      sW[kr][c] = W[(k0 + kr)*128 + c];
    }
    __syncthreads();
    #pragma unroll
    for (int kk=0; kk<32; kk++){
      float a[8], wv[4];
      #pragma unroll
      for (int i=0;i<8;i++) a[i] = sA[ty*8+i][kk];
      #pragma unroll
      for (int j=0;j<4;j++) wv[j] = sW[kk][tx + 32*j];
      #pragma unroll
      for (int i=0;i<8;i++)
        #pragma unroll
        for (int j=0;j<4;j++) acc[i][j] += a[i]*wv[j];
    }
    __syncthreads();
  }
  #pragma unroll
  for (int i=0;i<8;i++){
    size_t r = row0 + ty*8 + i;
    #pragma unroll
    for (int j=0;j<4;j++) C[r*128 + tx + 32*j] = f2b(acc[i][j]);
  }
}

// ---------------- logits ----------------
__global__ __launch_bounds__(256) void avec_dx(const void* X, const float* __restrict__ vdst,
                                               float* __restrict__ aDx, const int* __restrict__ fp){
  int f = *fp;
  int gid = blockIdx.x*256 + threadIdx.x;
  int n = gid >> 6, lane = gid & 63;
  float x1 = eluf(ldx(X, (size_t)n*128 + lane, f));
  float x2 = eluf(ldx(X, (size_t)n*128 + 64 + lane, f));
  float t0 = x1*vdst[lane*2+0] + x2*vdst[(lane+64)*2+0];
  float t1 = x1*vdst[lane*2+1] + x2*vdst[(lane+64)*2+1];
  #pragma unroll
  for (int o=32;o;o>>=1){ t0 += __shfl_xor(t0,o); t1 += __shfl_xor(t1,o); }
  if (lane == 0){ aDx[n*2+0] = t0; aDx[n*2+1] = t1; }
}

__global__ __launch_bounds__(256) void avec1(const bf16* __restrict__ AB,
    const float* __restrict__ att_is, const float* __restrict__ att_id, const float* __restrict__ att_xs,
    float* __restrict__ aSi, float* __restrict__ aDi, float* __restrict__ aSx){
  int gid = blockIdx.x*256 + threadIdx.x;
  int n = gid >> 6, lane = gid & 63;
  float va = b2f(AB[(size_t)n*128 + lane]);
  float s1 = va*att_is[lane], s2 = va*att_id[lane];
  float vb = b2f(AB[(size_t)n*128 + 64 + lane]);
  float s3 = vb*att_xs[lane];
  #pragma unroll
  for (int o=16;o;o>>=1){ s1 += __shfl_xor(s1,o); s2 += __shfl_xor(s2,o); s3 += __shfl_xor(s3,o); }
  if ((lane & 31) == 0){
    int h = lane >> 5;
    aSi[n*2+h] = s1; aDi[n*2+h] = s2; aSx[n*2+h] = s3;
  }
}

__global__ __launch_bounds__(256) void avec_pool(const bf16* __restrict__ P,
    const float* __restrict__ att_ps, const float* __restrict__ att_pd,
    float* __restrict__ aSp, float* __restrict__ aDp){
  int gid = blockIdx.x*256 + threadIdx.x;
  int n = gid >> 6, lane = gid & 63;
  float f0 = b2f(P[(size_t)n*128 + lane]);
  float f1 = b2f(P[(size_t)n*128 + 64 + lane]);
  float s0 = f0*att_ps[lane],    d0 = f0*att_pd[lane];
  float s1 = f1*att_ps[64+lane], d1 = f1*att_pd[64+lane];
  #pragma unroll
  for (int o=32;o;o>>=1){ s0+=__shfl_xor(s0,o); d0+=__shfl_xor(d0,o); s1+=__shfl_xor(s1,o); d1+=__shfl_xor(d1,o); }
  if (lane == 0){ aSp[n*2+0]=s0; aSp[n*2+1]=s1; aDp[n*2+0]=d0; aDp[n*2+1]=d1; }
}

// ---------------- GAT aggregation (one wave per dst, online softmax) ----------------
// out store flag-dispatched when fp!=null (true outputs); fp==null -> bf16 scratch.
template<int FD>
__global__ __launch_bounds__(256) void gat_agg(const int* __restrict__ offs, const int* __restrict__ srcs,
    const bf16* __restrict__ F,
    const float* __restrict__ aS, const float* __restrict__ aD,
    const float* __restrict__ bias, int self_loops,
    void* out, size_t obase, int col_off, size_t gbase, const int* __restrict__ fp){
  int f = fp ? *fp : 0;
  bool do_gather = (fp != nullptr);
  int gid = blockIdx.x*256 + threadIdx.x;
  int n = gid >> 6, lane = gid & 63;
  constexpr int NP = FD/64;
  float aDv[NP], m[NP], s[NP], acc[NP];
  int ff[NP], hh[NP];
  #pragma unroll
  for (int k=0;k<NP;k++){
    ff[k] = lane + 64*k;
    hh[k] = (FD==64) ? (lane>>5) : k;
    aDv[k] = aD[n*2 + hh[k]];
    m[k] = -1e30f; s[k] = 0.f; acc[k] = 0.f;
  }
  if (self_loops){
    #pragma unroll
    for (int k=0;k<NP;k++){
      float e = lrelu(aS[n*2+hh[k]] + aDv[k]);
      m[k] = e; s[k] = 1.f;
      acc[k] = b2f(F[(size_t)n*128 + ff[k]]);
    }
  }
  int beg = offs[n], end = offs[n+1];
  for (int j=beg; j<end; ++j){
    int sn = srcs[j];
    #pragma unroll
    for (int k=0;k<NP;k++){
      float e = lrelu(aS[sn*2+hh[k]] + aDv[k]);
      float fv = b2f(F[(size_t)sn*128 + ff[k]]);
      float mn = fmaxf(m[k], e);
      float cc = expf(m[k] - mn);
      float p  = expf(e - mn);
      s[k]   = s[k]*cc + p;
      acc[k] = acc[k]*cc + p*fv;
      m[k] = mn;
    }
  }
  bool gw = do_gather && ((n & 127) == 127);
  #pragma unroll
  for (int k=0;k<NP;k++){
    float o = acc[k]/(s[k] + 1e-16f) + bias[ff[k]];
    size_t oi = obase + (size_t)n*128 + col_off + ff[k];
    if (f) ((float*)out)[oi] = o; else ((bf16*)out)[oi] = f2b(o);
    if (gw){
      size_t gi = gbase + (size_t)(n>>7)*FD + ff[k];
      if (f) ((float*)out)[gi] = o; else ((bf16*)out)[gi] = f2b(o);
    }
  }
}

// ---------------- graph LayerNorm + ELU, in place on bf16 scratch ----------------
__global__ __launch_bounds__(256) void graph_ln(bf16* R_, const float* __restrict__ wv, const float* __restrict__ bv){
  __shared__ float sh[4];
  int g = blockIdx.x, t = threadIdx.x;
  bf16* R = R_ + (size_t)g*16384;
  float sum = 0.f;
  for (int i=t; i<16384; i+=256) sum += b2f(R[i]);
  #pragma unroll
  for (int o=32;o;o>>=1) sum += __shfl_xor(sum,o);
  if ((t&63)==0) sh[t>>6] = sum;
  __syncthreads();
  float mean = (sh[0]+sh[1]+sh[2]+sh[3]) * (1.f/16384.f);
  __syncthreads();
  float vs = 0.f;
  for (int i=t; i<16384; i+=256){ float d = b2f(R[i]) - mean; vs += d*d; }
  #pragma unroll
  for (int o=32;o;o>>=1) vs += __shfl_xor(vs,o);
  if ((t&63)==0) sh[t>>6] = vs;
  __syncthreads();
  float var = (sh[0]+sh[1]+sh[2]+sh[3]) * (1.f/16384.f);
  float rstd = rsqrtf(var + 1e-5f);
  for (int i=t; i<16384; i+=256){
    int c = i & 127;
    float y = (b2f(R[i]) - mean)*rstd*wv[c] + bv[c];
    R[i] = f2b(y > 0.f ? y : expm1f(y));
  }
}

extern "C" void kernel_launch(void* const* d_in, const int* in_sizes, int n_in,
                              void* d_out, int out_size, void* d_ws, size_t ws_size,
                              hipStream_t stream){
  (void)in_sizes; (void)n_in; (void)out_size; (void)ws_size;
  const void* h_x = d_in[0];
  const void* t_x = d_in[1];
  const int* h_ei = (const int*)d_in[2];
  const int* t_ei = (const int*)d_in[3];
  const int* b_ei = (const int*)d_in[4];

  // ---- workspace layout (~82 MB) ----
  char* base = (char*)d_ws;
  size_t off = 0;
  auto alloc = [&](size_t bytes)->char*{ char* p = base + off; off += (bytes + 255) & ~(size_t)255; return p; };
  bf16* AB    = (bf16*)alloc((size_t)NN*128*2);  // layer-1 feats (h then t); later P_h
  bf16* Pt    = (bf16*)alloc((size_t)NN*128*2);  // pool feats t
  int* srcs   = (int*)alloc((size_t)NE*4);
  int* offs   = (int*)alloc((size_t)(NN+1)*4);
  int* counts = (int*)alloc((size_t)NN*4);
  int* bsums  = (int*)alloc((size_t)512*4);
  float* aSi  = (float*)alloc((size_t)NN*2*4);
  float* aDi  = (float*)alloc((size_t)NN*2*4);
  float* aSx  = (float*)alloc((size_t)NN*2*4);
  float* aDx_h= (float*)alloc((size_t)NN*2*4);
  float* aDx_t= (float*)alloc((size_t)NN*2*4);
  float* Wc1  = (float*)alloc(16384*4);
  float* Wp   = (float*)alloc(16384*4);
  float* vdst = (float*)alloc(256*4);
  float* sm   = (float*)alloc(960*4);
  int* flag   = (int*)alloc(256);

  // layer-1 rep/nx scratch: first 2*NN*128 bf16 of d_out = 67.1 MB, safe under
  // either output dtype (out_size*2 bytes = 68.2 MB minimum buffer size).
  bf16* repS  = (bf16*)d_out;
  bf16* rep_h = repS;
  bf16* rep_t = repS + (size_t)NN*128;

  auto csr = [&](const int* sp, const int* dp){
    zero_ints<<<512,256,0,stream>>>(counts, NN);
    hist1<<<4096,256,0,stream>>>(dp, counts);
    scan_a<<<512,256,0,stream>>>(counts, offs, bsums);
    scan_b<<<1,512,0,stream>>>(bsums);
    scan_c<<<512,256,0,stream>>>(offs, bsums, counts);
    scatter1<<<4096,256,0,stream>>>(sp, dp, counts, srcs);
  };

  detect_dtype<<<1,64,0,stream>>>((const unsigned short*)h_x, flag);

  prep_kernel<<<1,256,0,stream>>>(d_in[9], d_in[13], d_in[14], d_in[16], d_in[18],
      d_in[10], d_in[11], d_in[15], d_in[19], d_in[20],
      d_in[12], d_in[17], d_in[21], d_in[22], d_in[23],
      Wc1, Wp, vdst, sm, flag);

  avec_dx<<<32768,256,0,stream>>>(h_x, vdst, aDx_h, flag);
  avec_dx<<<32768,256,0,stream>>>(t_x, vdst, aDx_t, flag);

  // ---- phase A: h-side layer-1 ----
  gemm128<true><<<2048,256,0,stream>>>(h_x, Wc1, AB, flag);
  avec1<<<32768,256,0,stream>>>(AB, sm+0, sm+64, sm+128, aSi, aDi, aSx);
  csr(h_ei, h_ei + NE);
  gat_agg<64><<<32768,256,0,stream>>>(offs, srcs, AB,    aSi, aDi,  sm+448, 1, repS, 0, 0,  0, nullptr);
  csr(b_ei, b_ei + NE);
  gat_agg<64><<<32768,256,0,stream>>>(offs, srcs, AB+64, aSx, aDx_t, sm+512, 0, repS, (size_t)NN*128, 64, 0, nullptr);

  // ---- phase B: t-side layer-1 ----
  gemm128<true><<<2048,256,0,stream>>>(t_x, Wc1, AB, flag);
  avec1<<<32768,256,0,stream>>>(AB, sm+0, sm+64, sm+128, aSi, aDi, aSx);
  csr(t_ei, t_ei + NE);
  gat_agg<64><<<32768,256,0,stream>>>(offs, srcs, AB,    aSi, aDi,  sm+448, 1, repS, (size_t)NN*128, 0, 0, nullptr);
  csr(b_ei + NE, b_ei);
  gat_agg<64><<<32768,256,0,stream>>>(offs, srcs, AB+64, aSx, aDx_h, sm+512, 0, repS, 0, 64, 0, nullptr);

  // ---- graph LayerNorm + ELU in place (2048 graph-slices across both halves) ----
  graph_ln<<<2048,256,0,stream>>>(repS, sm+704, sm+832);

  // ---- pool feats: BOTH gemms before any final write (nx must stay live) ----
  gemm128<false><<<2048,256,0,stream>>>(rep_h, Wp, AB, nullptr);   // P_h
  gemm128<false><<<2048,256,0,stream>>>(rep_t, Wp, Pt, nullptr);   // P_t

  // ---- pool GATs -> d_out (flag-dispatched stores; overwrite now-dead nx) ----
  size_t gb_h = (size_t)2*NN*128;
  size_t gb_t = gb_h + (size_t)NG*128;
  avec_pool<<<32768,256,0,stream>>>(AB, sm+192, sm+320, aSi, aDi);
  csr(h_ei, h_ei + NE);
  gat_agg<128><<<32768,256,0,stream>>>(offs, srcs, AB, aSi, aDi, sm+576, 1, d_out, 0, 0, gb_h, flag);

  avec_pool<<<32768,256,0,stream>>>(Pt, sm+192, sm+320, aSi, aDi);
  csr(t_ei, t_ei + NE);
  gat_agg<128><<<32768,256,0,stream>>>(offs, srcs, Pt, aSi, aDi, sm+576, 1, d_out, (size_t)NN*128, 0, gb_t, flag);
}

// Round 5
// 1769.250 us; speedup vs baseline: 1.3335x; 1.3335x over previous
//
#include <hip/hip_runtime.h>
#include <hip/hip_bf16.h>

#define NN 131072   // total nodes (1024 graphs x 128)
#define NG 1024     // graphs
#define NE 1048576  // edges per edge set

typedef __hip_bfloat16 bf16;

__device__ __forceinline__ float b2f(bf16 v){ return __bfloat162float(v); }
__device__ __forceinline__ bf16 f2b(float v){ return __float2bfloat16(v); }
__device__ __forceinline__ float eluf(float x){ return x > 0.f ? x : expm1f(x); }
__device__ __forceinline__ float lrelu(float x){ return x >= 0.f ? x : 0.2f*x; }

// flag-dispatched load: f=1 -> buffer is float32, f=0 -> bf16
__device__ __forceinline__ float ldx(const void* p, size_t i, int f){
  return f ? ((const float*)p)[i] : b2f(((const bf16*)p)[i]);
}
// readlane broadcast (j uniform)
__device__ __forceinline__ float rlf(float v, int j){
  return __uint_as_float((unsigned)__builtin_amdgcn_readlane((int)__float_as_uint(v), j));
}

struct EPtrs { const int *s0,*d0,*s1,*d1,*s2,*d2,*s3,*d3; };

// ---------------- input dtype probe (validated round 4) ----------------
__global__ void detect_dtype(const unsigned short* __restrict__ x, int* __restrict__ flag){
  if (blockIdx.x==0 && threadIdx.x==0){
    int bad = 0;
    for (int i=0;i<2048;i++){
      unsigned short e = (x[i] >> 7) & 0xFF;
      if (e == 0xFF) bad++;
      else if (e >= 0x90) bad++;
      else if (e != 0 && e < 0x60) bad++;
    }
    *flag = (bad > 64) ? 1 : 0;
  }
}

__global__ __launch_bounds__(256) void zero_ints(int* __restrict__ p, int n){
  int i = blockIdx.x*256 + threadIdx.x;
  if (i < n) p[i] = 0;
}

// ---------------- CSR build: 4 edge sets batched, built once ----------------
__global__ __launch_bounds__(256) void hist4(EPtrs ep, int* __restrict__ counts){
  int set = blockIdx.y;
  int e = blockIdx.x*256 + threadIdx.x;
  const int* dp = set==0 ? ep.d0 : set==1 ? ep.d1 : set==2 ? ep.d2 : ep.d3;
  atomicAdd(&counts[set*NN + dp[e]], 1);
}

__global__ __launch_bounds__(256) void scan_a4(const int* __restrict__ counts, int* __restrict__ offs, int* __restrict__ bsums){
  __shared__ int sh[256];
  int set = blockIdx.y, b = blockIdx.x, t = threadIdx.x;
  int i = b*256 + t;
  int v = counts[set*NN + i];
  int val = v; sh[t] = v; __syncthreads();
  for (int d=1; d<256; d<<=1){
    int add = (t >= d) ? sh[t-d] : 0;
    __syncthreads();
    val += add; sh[t] = val;
    __syncthreads();
  }
  offs[(size_t)set*(NN+1) + i] = val - v;
  if (t == 255) bsums[set*512 + b] = val;
}

__global__ __launch_bounds__(512) void scan_b4(int* __restrict__ bsums){
  __shared__ int sh[512];
  int set = blockIdx.x, t = threadIdx.x;
  int v = bsums[set*512 + t];
  int val = v; sh[t] = v; __syncthreads();
  for (int d=1; d<512; d<<=1){
    int add = (t >= d) ? sh[t-d] : 0;
    __syncthreads();
    val += add; sh[t] = val;
    __syncthreads();
  }
  bsums[set*512 + t] = val - v;
}

__global__ __launch_bounds__(256) void scan_c4(int* __restrict__ offs, const int* __restrict__ bsums, int* __restrict__ cursor){
  int set = blockIdx.y;
  int i = blockIdx.x*256 + threadIdx.x;
  int v = offs[(size_t)set*(NN+1) + i] + bsums[set*512 + blockIdx.x];
  offs[(size_t)set*(NN+1) + i] = v;
  cursor[set*NN + i] = v;
  if (i == 0) offs[(size_t)set*(NN+1) + NN] = NE;
}

__global__ __launch_bounds__(256) void scatter4(EPtrs ep, int* __restrict__ cursor, int* __restrict__ srcs){
  int set = blockIdx.y;
  int e = blockIdx.x*256 + threadIdx.x;
  const int* sp = set==0 ? ep.s0 : set==1 ? ep.s1 : set==2 ? ep.s2 : ep.s3;
  const int* dp = set==0 ? ep.d0 : set==1 ? ep.d1 : set==2 ? ep.d2 : ep.d3;
  int p = atomicAdd(&cursor[set*NN + dp[e]], 1);
  srcs[(size_t)set*NE + p] = sp[e];
}

// ---------------- weight prep (validated round 4) ----------------
// sm: 0 att_is[64] | 64 att_id[64] | 128 att_xs[64] | 192 att_ps[128] | 320 att_pd[128] |
//     448 b_intra[64] | 512 b_inter[64] | 576 b_pool[128] | 704 ln_w[128] | 832 ln_b[128]
__global__ __launch_bounds__(256) void prep_kernel(
    const void* w_intra, const void* w_isrc, const void* w_idst, const void* att_xd, const void* w_pool,
    const void* att_is, const void* att_id, const void* att_xs,
    const void* att_ps, const void* att_pd,
    const void* b_intra, const void* b_inter, const void* b_pool,
    const void* ln_w, const void* ln_b,
    float* __restrict__ Wc1, float* __restrict__ Wp, float* __restrict__ vdst, float* __restrict__ sm,
    const int* __restrict__ fp){
  int f = *fp;
  int t = threadIdx.x;
  for (int i=t; i<16384; i+=256){
    int k = i>>7, j = i&127;
    Wc1[i] = (j < 64) ? ldx(w_intra, k*64 + j, f) : ldx(w_isrc, k*64 + (j-64), f);
    Wp[i]  = ldx(w_pool, i, f);
  }
  {
    int k = t>>1, h = t&1; float a = 0.f;
    for (int c=0;c<32;c++) a += ldx(w_idst, k*64 + h*32 + c, f) * ldx(att_xd, h*32 + c, f);
    vdst[t] = a;
  }
  if (t < 64){
    sm[t]     = ldx(att_is, t, f);
    sm[64+t]  = ldx(att_id, t, f);
    sm[128+t] = ldx(att_xs, t, f);
    sm[448+t] = ldx(b_intra, t, f);
    sm[512+t] = ldx(b_inter, t, f);
  }
  if (t < 128){
    sm[192+t] = ldx(att_ps, t, f);
    sm[320+t] = ldx(att_pd, t, f);
    sm[576+t] = ldx(b_pool, t, f);
    sm[704+t] = ldx(ln_w, t, f);
    sm[832+t] = ldx(ln_b, t, f);
  }
}

// ---------------- GEMM: C[N,128] = act(A[N,128]) @ W[128,128] ----------------
// fp!=null: A is raw input (flag dtype). fp==null: A is bf16 scratch at flag-selected offset.
template<bool ELU>
__global__ __launch_bounds__(256) void gemm128(const void* A, const float* __restrict__ W, bf16* __restrict__ C,
                                               const int* __restrict__ fp,
                                               const int* __restrict__ fsel, size_t aoff_bf, size_t aoff_f32){
  int f = fp ? *fp : 0;
  const bf16* Ab = (const bf16*)A + ((fp == nullptr && fsel && *fsel) ? aoff_f32 : aoff_bf);
  __shared__ float sA[64][33];
  __shared__ float sW[32][128];
  int tid = threadIdx.x;
  int tx = tid & 31, ty = tid >> 5;
  size_t row0 = (size_t)blockIdx.x * 64;
  float acc[8][4] = {};
  for (int k0 = 0; k0 < 128; k0 += 32){
    #pragma unroll
    for (int i=0;i<8;i++){
      int idx = tid + i*256;
      int r = idx >> 5, kk = idx & 31;
      size_t ai = (row0 + r)*128 + k0 + kk;
      float v = fp ? ldx(A, ai, f) : b2f(Ab[ai]);
      if (ELU) v = eluf(v);
      sA[r][kk] = v;
    }
    #pragma unroll
    for (int i=0;i<16;i++){
      int idx = tid + i*256;
      int kr = idx >> 7, c = idx & 127;
      sW[kr][c] = W[(k0 + kr)*128 + c];
    }
    __syncthreads();
    #pragma unroll
    for (int kk=0; kk<32; kk++){
      float a[8], wv[4];
      #pragma unroll
      for (int i=0;i<8;i++) a[i] = sA[ty*8+i][kk];
      #pragma unroll
      for (int j=0;j<4;j++) wv[j] = sW[kk][tx + 32*j];
      #pragma unroll
      for (int i=0;i<8;i++)
        #pragma unroll
        for (int j=0;j<4;j++) acc[i][j] += a[i]*wv[j];
    }
    __syncthreads();
  }
  #pragma unroll
  for (int i=0;i<8;i++){
    size_t r = row0 + ty*8 + i;
    #pragma unroll
    for (int j=0;j<4;j++) C[r*128 + tx + 32*j] = f2b(acc[i][j]);
  }
}

// ---------------- logits ----------------
__global__ __launch_bounds__(256) void avec_dx(const void* X, const float* __restrict__ vdst,
                                               float* __restrict__ aDx, const int* __restrict__ fp){
  int f = *fp;
  int gid = blockIdx.x*256 + threadIdx.x;
  int n = gid >> 6, lane = gid & 63;
  float x1 = eluf(ldx(X, (size_t)n*128 + lane, f));
  float x2 = eluf(ldx(X, (size_t)n*128 + 64 + lane, f));
  float t0 = x1*vdst[lane*2+0] + x2*vdst[(lane+64)*2+0];
  float t1 = x1*vdst[lane*2+1] + x2*vdst[(lane+64)*2+1];
  #pragma unroll
  for (int o=32;o;o>>=1){ t0 += __shfl_xor(t0,o); t1 += __shfl_xor(t1,o); }
  if (lane == 0){ aDx[n*2+0] = t0; aDx[n*2+1] = t1; }
}

__global__ __launch_bounds__(256) void avec1(const bf16* __restrict__ AB,
    const float* __restrict__ att_is, const float* __restrict__ att_id, const float* __restrict__ att_xs,
    float* __restrict__ aSi, float* __restrict__ aDi, float* __restrict__ aSx){
  int gid = blockIdx.x*256 + threadIdx.x;
  int n = gid >> 6, lane = gid & 63;
  float va = b2f(AB[(size_t)n*128 + lane]);
  float s1 = va*att_is[lane], s2 = va*att_id[lane];
  float vb = b2f(AB[(size_t)n*128 + 64 + lane]);
  float s3 = vb*att_xs[lane];
  #pragma unroll
  for (int o=16;o;o>>=1){ s1 += __shfl_xor(s1,o); s2 += __shfl_xor(s2,o); s3 += __shfl_xor(s3,o); }
  if ((lane & 31) == 0){
    int h = lane >> 5;
    aSi[n*2+h] = s1; aDi[n*2+h] = s2; aSx[n*2+h] = s3;
  }
}

__global__ __launch_bounds__(256) void avec_pool(const bf16* __restrict__ P,
    const float* __restrict__ att_ps, const float* __restrict__ att_pd,
    float* __restrict__ aSp, float* __restrict__ aDp){
  int gid = blockIdx.x*256 + threadIdx.x;
  int n = gid >> 6, lane = gid & 63;
  float f0 = b2f(P[(size_t)n*128 + lane]);
  float f1 = b2f(P[(size_t)n*128 + 64 + lane]);
  float s0 = f0*att_ps[lane],    d0 = f0*att_pd[lane];
  float s1 = f1*att_ps[64+lane], d1 = f1*att_pd[64+lane];
  #pragma unroll
  for (int o=32;o;o>>=1){ s0+=__shfl_xor(s0,o); d0+=__shfl_xor(d0,o); s1+=__shfl_xor(s1,o); d1+=__shfl_xor(d1,o); }
  if (lane == 0){ aSp[n*2+0]=s0; aSp[n*2+1]=s1; aDp[n*2+0]=d0; aDp[n*2+1]=d1; }
}

// ---------------- GAT aggregation v2: lane-parallel softmax over edges ----------------
// One wave per dst node. Chunk of 64 edges: lane j owns edge j (both heads), computes
// logits once; wave-reduce max & sum; feature pass broadcasts (p0,p1,src) via readlane
// and does one coalesced gather + FMA per lane per edge (2-way unrolled).
// fp==null -> bf16 scratch store; else store dtype by *fp. fsel picks scratch base.
template<int FD>
__global__ __launch_bounds__(256) void gat_agg2(const int* __restrict__ offs, const int* __restrict__ srcs,
    const bf16* __restrict__ F,
    const float* __restrict__ aS, const float* __restrict__ aD,
    const float* __restrict__ bias, int self_loops,
    void* out, size_t obase_bf, size_t obase_f32, int col_off, size_t gbase,
    const int* __restrict__ fp, const int* __restrict__ fsel){
  int fo = fp ? *fp : -1;
  size_t obase = (fsel && *fsel) ? obase_f32 : obase_bf;
  int gid = blockIdx.x*256 + threadIdx.x;
  int n = gid >> 6, lane = gid & 63;
  int beg = offs[n];
  int deg = offs[n+1] - beg;
  int total = deg + (self_loops ? 1 : 0);
  float2 ad = *(const float2*)(aD + (size_t)n*2);
  float m0 = -INFINITY, m1 = -INFINITY, s0 = 0.f, s1 = 0.f;
  float aA = 0.f, aB = 0.f, a1A = 0.f, a1B = 0.f;

  for (int c = 0; c < total; c += 64){
    int i = c + lane;
    int sn = n;                       // self-loop item (i == deg) uses n
    float e0 = -INFINITY, e1 = -INFINITY;
    if (i < total){
      if (i < deg) sn = srcs[beg + i];
      float2 as = *(const float2*)(aS + (size_t)sn*2);
      e0 = lrelu(as.x + ad.x);
      e1 = lrelu(as.y + ad.y);
    }
    float cm0 = e0, cm1 = e1;
    #pragma unroll
    for (int o=32;o;o>>=1){ cm0 = fmaxf(cm0, __shfl_xor(cm0,o)); cm1 = fmaxf(cm1, __shfl_xor(cm1,o)); }
    float nm0 = fmaxf(m0, cm0), nm1 = fmaxf(m1, cm1);
    float sc0 = __expf(m0 - nm0), sc1 = __expf(m1 - nm1);   // first chunk: exp(-inf)=0
    m0 = nm0; m1 = nm1;
    float p0 = __expf(e0 - nm0), p1 = __expf(e1 - nm1);     // inactive lanes -> 0
    float cs0 = p0, cs1 = p1;
    #pragma unroll
    for (int o=32;o;o>>=1){ cs0 += __shfl_xor(cs0,o); cs1 += __shfl_xor(cs1,o); }
    s0 = s0*sc0 + cs0; s1 = s1*sc1 + cs1;
    if (FD==64){ float sc = (lane<32)? sc0 : sc1; aA *= sc; aB *= sc; }
    else { aA *= sc0; aB *= sc0; a1A *= sc1; a1B *= sc1; }

    int cnt = min(64, total - c);
    int c2 = cnt & ~1;
    for (int j=0;j<c2;j+=2){
      int sa = __builtin_amdgcn_readlane(sn, j);
      int sb = __builtin_amdgcn_readlane(sn, j+1);
      float pa0 = rlf(p0,j),   pa1 = rlf(p1,j);
      float pb0 = rlf(p0,j+1), pb1 = rlf(p1,j+1);
      if (FD==64){
        float pva = (lane<32)? pa0 : pa1;
        float pvb = (lane<32)? pb0 : pb1;
        aA += pva * b2f(F[(size_t)sa*128 + lane]);
        aB += pvb * b2f(F[(size_t)sb*128 + lane]);
      } else {
        aA  += pa0 * b2f(F[(size_t)sa*128 + lane]);
        a1A += pa1 * b2f(F[(size_t)sa*128 + 64 + lane]);
        aB  += pb0 * b2f(F[(size_t)sb*128 + lane]);
        a1B += pb1 * b2f(F[(size_t)sb*128 + 64 + lane]);
      }
    }
    if (cnt & 1){
      int j = cnt - 1;
      int sa = __builtin_amdgcn_readlane(sn, j);
      float pa0 = rlf(p0,j), pa1 = rlf(p1,j);
      if (FD==64){
        float pva = (lane<32)? pa0 : pa1;
        aA += pva * b2f(F[(size_t)sa*128 + lane]);
      } else {
        aA  += pa0 * b2f(F[(size_t)sa*128 + lane]);
        a1A += pa1 * b2f(F[(size_t)sa*128 + 64 + lane]);
      }
    }
  }

  if (FD==64){
    float ssel = (lane<32)? s0 : s1;
    float o = (aA + aB)/(ssel + 1e-16f) + bias[lane];
    size_t oi = obase + (size_t)n*128 + col_off + lane;
    if (fo > 0) ((float*)out)[oi] = o;
    else ((bf16*)out)[oi] = f2b(o);
  } else {
    float o0 = (aA + aB)/(s0 + 1e-16f) + bias[lane];
    float o1 = (a1A + a1B)/(s1 + 1e-16f) + bias[64+lane];
    size_t oi = obase + (size_t)n*128;
    bool gw = (fp != nullptr) && ((n & 127) == 127);
    size_t gi = gbase + (size_t)(n>>7)*128;
    if (fo > 0){
      ((float*)out)[oi+lane] = o0; ((float*)out)[oi+64+lane] = o1;
      if (gw){ ((float*)out)[gi+lane]=o0; ((float*)out)[gi+64+lane]=o1; }
    } else {
      ((bf16*)out)[oi+lane] = f2b(o0); ((bf16*)out)[oi+64+lane] = f2b(o1);
      if (gw){ ((bf16*)out)[gi+lane]=f2b(o0); ((bf16*)out)[gi+64+lane]=f2b(o1); }
    }
  }
}

// ---------------- graph LayerNorm + ELU, in place on bf16 scratch ----------------
__global__ __launch_bounds__(256) void graph_ln(bf16* R_, size_t off_bf, size_t off_f32,
    const int* __restrict__ fsel, const float* __restrict__ wv, const float* __restrict__ bv){
  __shared__ float sh[4];
  int g = blockIdx.x, t = threadIdx.x;
  bf16* R = R_ + ((*fsel) ? off_f32 : off_bf) + (size_t)g*16384;
  float sum = 0.f;
  for (int i=t; i<16384; i+=256) sum += b2f(R[i]);
  #pragma unroll
  for (int o=32;o;o>>=1) sum += __shfl_xor(sum,o);
  if ((t&63)==0) sh[t>>6] = sum;
  __syncthreads();
  float mean = (sh[0]+sh[1]+sh[2]+sh[3]) * (1.f/16384.f);
  __syncthreads();
  float vs = 0.f;
  for (int i=t; i<16384; i+=256){ float d = b2f(R[i]) - mean; vs += d*d; }
  #pragma unroll
  for (int o=32;o;o>>=1) vs += __shfl_xor(vs,o);
  if ((t&63)==0) sh[t>>6] = vs;
  __syncthreads();
  float var = (sh[0]+sh[1]+sh[2]+sh[3]) * (1.f/16384.f);
  float rstd = rsqrtf(var + 1e-5f);
  for (int i=t; i<16384; i+=256){
    int c = i & 127;
    float y = (b2f(R[i]) - mean)*rstd*wv[c] + bv[c];
    R[i] = f2b(y > 0.f ? y : expm1f(y));
  }
}

extern "C" void kernel_launch(void* const* d_in, const int* in_sizes, int n_in,
                              void* d_out, int out_size, void* d_ws, size_t ws_size,
                              hipStream_t stream){
  (void)in_sizes; (void)n_in; (void)out_size; (void)ws_size;
  const void* h_x = d_in[0];
  const void* t_x = d_in[1];
  const int* h_ei = (const int*)d_in[2];
  const int* t_ei = (const int*)d_in[3];
  const int* b_ei = (const int*)d_in[4];

  // ---- workspace (~60 MB) ----
  char* base = (char*)d_ws;
  size_t off = 0;
  auto alloc = [&](size_t bytes)->char*{ char* p = base + off; off += (bytes + 255) & ~(size_t)255; return p; };
  bf16* AB     = (bf16*)alloc((size_t)NN*128*2);   // layer-1 feats (h then t); pool feats (h then t)
  int* srcs4   = (int*)alloc((size_t)4*NE*4);
  int* offs4   = (int*)alloc((size_t)4*(NN+1)*4);
  int* counts4 = (int*)alloc((size_t)4*NN*4);      // also scatter cursor
  int* bsums4  = (int*)alloc((size_t)4*512*4);
  float* aSi   = (float*)alloc((size_t)NN*2*4);    // per-phase; pool aSp
  float* aDi   = (float*)alloc((size_t)NN*2*4);    // per-phase; pool aDp
  float* aSx   = (float*)alloc((size_t)NN*2*4);
  float* aDx_h = (float*)alloc((size_t)NN*2*4);
  float* aDx_t = (float*)alloc((size_t)NN*2*4);
  float* Wc1   = (float*)alloc(16384*4);
  float* Wp    = (float*)alloc(16384*4);
  float* vdst  = (float*)alloc(256*4);
  float* sm    = (float*)alloc(960*4);
  int* flag    = (int*)alloc(256);

  // rep/nx scratch in d_out (bf16). rep_h at elem 0 (both modes).
  // rep_t: bf16 mode -> elem NN*128 (bytes 33.5-67.1MB); f32 mode -> elem 2*NN*128
  // (bytes 67.1-134.2MB, just past the f32 h-rows) so pool-gat h's f32 writes
  // (bytes 0-67.1MB + gather at 134.2MB) never touch it. Verified disjoint both modes.
  const size_t REPT_BF = (size_t)NN*128, REPT_F32 = (size_t)2*NN*128;

  detect_dtype<<<1,64,0,stream>>>((const unsigned short*)h_x, flag);

  // ---- CSR x4, built once: 0=h-intra 1=t-intra 2=bip h->t 3=bip t->h ----
  EPtrs ep;
  ep.s0 = h_ei;      ep.d0 = h_ei + NE;
  ep.s1 = t_ei;      ep.d1 = t_ei + NE;
  ep.s2 = b_ei;      ep.d2 = b_ei + NE;
  ep.s3 = b_ei + NE; ep.d3 = b_ei;
  zero_ints<<<2048,256,0,stream>>>(counts4, 4*NN);
  hist4<<<dim3(4096,4),256,0,stream>>>(ep, counts4);
  scan_a4<<<dim3(512,4),256,0,stream>>>(counts4, offs4, bsums4);
  scan_b4<<<4,512,0,stream>>>(bsums4);
  scan_c4<<<dim3(512,4),256,0,stream>>>(offs4, bsums4, counts4);
  scatter4<<<dim3(4096,4),256,0,stream>>>(ep, counts4, srcs4);

  prep_kernel<<<1,256,0,stream>>>(d_in[9], d_in[13], d_in[14], d_in[16], d_in[18],
      d_in[10], d_in[11], d_in[15], d_in[19], d_in[20],
      d_in[12], d_in[17], d_in[21], d_in[22], d_in[23],
      Wc1, Wp, vdst, sm, flag);

  avec_dx<<<32768,256,0,stream>>>(h_x, vdst, aDx_h, flag);
  avec_dx<<<32768,256,0,stream>>>(t_x, vdst, aDx_t, flag);

  const int* offs_h = offs4;
  const int* offs_t = offs4 + (NN+1);
  const int* offs_ht= offs4 + 2*(NN+1);
  const int* offs_th= offs4 + 3*(NN+1);
  const int* srcs_h = srcs4;
  const int* srcs_t = srcs4 + NE;
  const int* srcs_ht= srcs4 + (size_t)2*NE;
  const int* srcs_th= srcs4 + (size_t)3*NE;

  // ---- phase A: h-side layer-1 ----
  gemm128<true><<<2048,256,0,stream>>>(h_x, Wc1, AB, flag, nullptr, 0, 0);
  avec1<<<32768,256,0,stream>>>(AB, sm+0, sm+64, sm+128, aSi, aDi, aSx);
  gat_agg2<64><<<32768,256,0,stream>>>(offs_h,  srcs_h,  AB,    aSi, aDi,  sm+448, 1,
      d_out, 0, 0, 0, 0, nullptr, flag);
  gat_agg2<64><<<32768,256,0,stream>>>(offs_ht, srcs_ht, AB+64, aSx, aDx_t, sm+512, 0,
      d_out, REPT_BF, REPT_F32, 64, 0, nullptr, flag);

  // ---- phase B: t-side layer-1 ----
  gemm128<true><<<2048,256,0,stream>>>(t_x, Wc1, AB, flag, nullptr, 0, 0);
  avec1<<<32768,256,0,stream>>>(AB, sm+0, sm+64, sm+128, aSi, aDi, aSx);
  gat_agg2<64><<<32768,256,0,stream>>>(offs_t,  srcs_t,  AB,    aSi, aDi,  sm+448, 1,
      d_out, REPT_BF, REPT_F32, 0, 0, nullptr, flag);
  gat_agg2<64><<<32768,256,0,stream>>>(offs_th, srcs_th, AB+64, aSx, aDx_h, sm+512, 0,
      d_out, 0, 0, 64, 0, nullptr, flag);

  // ---- graph LayerNorm + ELU in place ----
  graph_ln<<<NG,256,0,stream>>>((bf16*)d_out, 0, 0, flag, sm+704, sm+832);
  graph_ln<<<NG,256,0,stream>>>((bf16*)d_out, REPT_BF, REPT_F32, flag, sm+704, sm+832);

  // ---- pool h: nx_h -> P_h (AB) -> final h rows + gather ----
  size_t gb_h = (size_t)2*NN*128;
  size_t gb_t = gb_h + (size_t)NG*128;
  gemm128<false><<<2048,256,0,stream>>>(d_out, Wp, AB, nullptr, flag, 0, 0);
  avec_pool<<<32768,256,0,stream>>>(AB, sm+192, sm+320, aSi, aDi);
  gat_agg2<128><<<32768,256,0,stream>>>(offs_h, srcs_h, AB, aSi, aDi, sm+576, 1,
      d_out, 0, 0, 0, gb_h, flag, flag);

  // ---- pool t ----
  gemm128<false><<<2048,256,0,stream>>>(d_out, Wp, AB, nullptr, flag, REPT_BF, REPT_F32);
  avec_pool<<<32768,256,0,stream>>>(AB, sm+192, sm+320, aSi, aDi);
  gat_agg2<128><<<32768,256,0,stream>>>(offs_t, srcs_t, AB, aSi, aDi, sm+576, 1,
      d_out, (size_t)NN*128, (size_t)NN*128, 0, gb_t, flag, flag);
}